// Round 1
// baseline (4130.105 us; speedup 1.0000x reference)
//
#include <hip/hip_runtime.h>

typedef _Float16 f16;
typedef _Float16 half8 __attribute__((ext_vector_type(8)));
typedef _Float16 half4 __attribute__((ext_vector_type(4)));
typedef float f32x4 __attribute__((ext_vector_type(4)));

// Problem constants
#define BB 64
#define TT 2048
#define II 256
#define HH 256
#define G3 768

__global__ void cvt_f32_f16(const float* __restrict__ in, f16* __restrict__ out, int n) {
  int i = blockIdx.x * blockDim.x + threadIdx.x;
  if (i < n) out[i] = (f16)in[i];
}

// C[m][n] = sum_k A[m][k] * W[n][k] + bias[n]
// A: f32 [M][256] (rows contiguous), W: f16 [768][256], C: f16 [M][768]
// grid.x = M/64, block = 256 threads (4 waves). Tile: 64(M) x 48(N) chunks, K=256 resident.
__global__ __launch_bounds__(256, 2)
void gi_gemm(const float* __restrict__ A, const f16* __restrict__ W,
             const float* __restrict__ bias, f16* __restrict__ C) {
  const int tid = threadIdx.x;
  const int lane = tid & 63;
  const int w = tid >> 6;      // wave 0..3
  const int quad = lane >> 4;  // 0..3
  const int lq = lane & 15;
  const int m0 = blockIdx.x * 64;

  __shared__ __align__(16) f16 Al[64 * 264];  // pad rows to 264 halves (528 B, 16B-mult)
  __shared__ __align__(16) f16 Bl[48 * 264];

  // stage A tile: 64 rows x 256 f32 -> f16 LDS
#pragma unroll
  for (int i = 0; i < 16; ++i) {
    int f = i * 256 + tid;  // float4 index over 64x64
    int row = f >> 6;
    int c4 = f & 63;
    float4 v = ((const float4*)A)[(size_t)(m0 + row) * 64 + c4];
    half4 hv = {(f16)v.x, (f16)v.y, (f16)v.z, (f16)v.w};
    *(half4*)&Al[row * 264 + c4 * 4] = hv;
  }
  __syncthreads();

  // preload this wave's A-fragments for its 16-row strip (reused across all n-chunks)
  // A[m=lq][k = kc*32 + quad*8 + j]
  half8 af[8];
#pragma unroll
  for (int kc = 0; kc < 8; ++kc)
    af[kc] = *(half8*)&Al[(w * 16 + lq) * 264 + kc * 32 + quad * 8];

  for (int nc = 0; nc < 16; ++nc) {
    __syncthreads();  // previous chunk's compute done before Bl overwrite
    int n0 = nc * 48;
    // stage W chunk: 48 rows x 256 halves = 1536 half8
#pragma unroll
    for (int i = 0; i < 6; ++i) {
      int f = i * 256 + tid;
      int row = f >> 5;   // 32 half8 per row
      int c8 = f & 31;
      half8 v = ((const half8*)(W + (size_t)(n0 + row) * 256))[c8];
      *(half8*)&Bl[row * 264 + c8 * 8] = v;
    }
    __syncthreads();

    f32x4 acc[3] = {};
#pragma unroll
    for (int kc = 0; kc < 8; ++kc) {
#pragma unroll
      for (int nt = 0; nt < 3; ++nt) {
        half8 bf = *(half8*)&Bl[(nt * 16 + lq) * 264 + kc * 32 + quad * 8];
        acc[nt] = __builtin_amdgcn_mfma_f32_16x16x32_f16(af[kc], bf, acc[nt], 0, 0, 0);
      }
    }
    // C/D layout: col = lane&15, row = quad*4 + reg
#pragma unroll
    for (int nt = 0; nt < 3; ++nt) {
      int n = n0 + nt * 16 + lq;
      float bv = bias[n];
#pragma unroll
      for (int r = 0; r < 4; ++r) {
        int m = m0 + w * 16 + quad * 4 + r;
        C[(size_t)m * G3 + n] = (f16)(acc[nt][r] + bv);
      }
    }
  }
}

// One block per chain. 512 threads (8 waves). W_hh resident in VGPRs as f16 MFMA
// A-fragments (wave w owns rows w*96..w*96+95 -> 6 tiles x 8 k-chunks = 192 VGPRs).
// Per step: gh = Whh@h via mfma_16x16x32_f16 with h broadcast into all B columns,
// then waves 0..3 do the gate epilogue on 256 lanes.
template <bool IS_KEY>
__global__ __launch_bounds__(512, 2)
void gru_scan(const float* __restrict__ Whh, const float* __restrict__ bhh,
              const f16* __restrict__ GI, const float* __restrict__ gates,
              float* __restrict__ out, int T) {
  const int tid = threadIdx.x;
  const int lane = tid & 63;
  const int w = tid >> 6;      // 0..7
  const int quad = lane >> 4;  // 0..3
  const int lq = lane & 15;
  const int b = blockIdx.x;

  __shared__ __align__(16) f16 hh[256];    // h in f16 (matvec operand)
  __shared__ __align__(16) float hf[256];  // h in f32 (epilogue blend)
  __shared__ __align__(16) float gh[G3];   // matvec result

  // Load resident weight fragments: aw[t6][kc][j] = Whh[w*96 + t6*16 + lq][kc*32 + quad*8 + j]
  half8 aw[6][8];
#pragma unroll
  for (int t6 = 0; t6 < 6; ++t6) {
    const float* wr = Whh + (size_t)(w * 96 + t6 * 16 + lq) * 256;
#pragma unroll
    for (int kc = 0; kc < 8; ++kc) {
      int c = kc * 32 + quad * 8;
      float4 v0 = *(const float4*)(wr + c);
      float4 v1 = *(const float4*)(wr + c + 4);
      half8 h8 = {(f16)v0.x, (f16)v0.y, (f16)v0.z, (f16)v0.w,
                  (f16)v1.x, (f16)v1.y, (f16)v1.z, (f16)v1.w};
      aw[t6][kc] = h8;
    }
  }

  if (tid < 256) { hf[tid] = 0.f; hh[tid] = (f16)0.f; }

  // epilogue-lane persistent state (waves 0..3)
  float bh_r = 0.f, bh_i = 0.f, bh_n = 0.f;
  float g0r = 0.f, g0i = 0.f, g0n = 0.f;  // gi for step t
  float g1r = 0.f, g1i = 0.f, g1n = 0.f;  // gi for step t+1 (prefetch dist 2)
  const size_t gibase = (size_t)b * T * G3;
  if (tid < 256) {
    bh_r = bhh[tid]; bh_i = bhh[256 + tid]; bh_n = bhh[512 + tid];
    g0r = (float)GI[gibase + tid];
    g0i = (float)GI[gibase + 256 + tid];
    g0n = (float)GI[gibase + 512 + tid];
    if (T > 1) {
      g1r = (float)GI[gibase + G3 + tid];
      g1i = (float)GI[gibase + G3 + 256 + tid];
      g1n = (float)GI[gibase + G3 + 512 + tid];
    }
  }
  __syncthreads();

  for (int t = 0; t < T; ++t) {
    // ---- matvec: gh = Whh @ h (all 8 waves) ----
    f32x4 acc[6] = {};
#pragma unroll
    for (int kc = 0; kc < 8; ++kc) {
      // B[k][n] = h[32*kc + quad*8 + j] for every column n -> broadcast
      half8 bf = *(half8*)&hh[kc * 32 + quad * 8];
#pragma unroll
      for (int t6 = 0; t6 < 6; ++t6)
        acc[t6] = __builtin_amdgcn_mfma_f32_16x16x32_f16(aw[t6][kc], bf, acc[t6], 0, 0, 0);
    }
    // every column of D holds gh; column-0 lanes write it out
    if (lq == 0) {
#pragma unroll
      for (int t6 = 0; t6 < 6; ++t6)
        *(f32x4*)&gh[w * 96 + t6 * 16 + quad * 4] = acc[t6];
    }
    __syncthreads();

    // ---- epilogue (waves 0..3, one lane per hidden unit) ----
    if (tid < 256) {
      const int j = tid;
      // prefetch gi for t+2 (distance 2 hides HBM latency behind ~2 steps)
      float g2r = 0.f, g2i = 0.f, g2n = 0.f;
      if (t + 2 < T) {
        size_t p = gibase + (size_t)(t + 2) * G3;
        g2r = (float)GI[p + j];
        g2i = (float)GI[p + 256 + j];
        g2n = (float)GI[p + 512 + j];
      }
      float rr = g0r + bh_r + gh[j];
      float ii = g0i + bh_i + gh[256 + j];
      float hn = bh_n + gh[512 + j];
      float rg = 1.f / (1.f + __expf(-rr));
      float ig = 1.f / (1.f + __expf(-ii));
      float npre = g0n + rg * hn;
      float e2 = __expf(2.f * npre);
      float ng = 1.f - 2.f / (e2 + 1.f);  // tanh, robust at +-inf
      float hv = hf[j];
      float hy = ng + ig * (hv - ng);
      float hnew;
      if (IS_KEY) {
        out[((size_t)t * 4 + b) * 256 + j] = rg;  // collect reset gate
        hnew = hy;
      } else {
        out[((size_t)t * 64 + b) * 256 + j] = hy;  // output pre-gate hy
        float gm = (t < 16) ? gates[t * 256 + j] : 1.f;
        hnew = hy * gm;
      }
      hf[j] = hnew;
      hh[j] = (f16)hnew;
      g0r = g1r; g0i = g1i; g0n = g1n;
      g1r = g2r; g1i = g2i; g1n = g2n;
    }
    __syncthreads();
  }
}

__global__ void gate_mean(const float* __restrict__ rg, float* __restrict__ g) {
  int i = blockIdx.x * 256 + threadIdx.x;  // 16*256
  int l = i >> 8;
  int j = i & 255;
  float s = 0.f;
#pragma unroll
  for (int kb = 0; kb < 4; ++kb) s += rg[((size_t)l * 4 + kb) * 256 + j];
  g[i] = 0.25f * s;
}

extern "C" void kernel_launch(void* const* d_in, const int* in_sizes, int n_in,
                              void* d_out, int out_size, void* d_ws, size_t ws_size,
                              hipStream_t stream) {
  const float* x      = (const float*)d_in[0];  // [64][2048][256]
  const float* wm_key = (const float*)d_in[1];  // [4][16][256] -> 64 rows of 256
  const float* w_ih   = (const float*)d_in[2];  // [768][256]
  const float* w_hh   = (const float*)d_in[3];  // [768][256]
  const float* b_ih   = (const float*)d_in[4];  // [768]
  const float* b_hh   = (const float*)d_in[5];  // [768]
  float* out = (float*)d_out;                   // [2048][64][256]

  char* ws = (char*)d_ws;
  const size_t GI_OFF  = 0;                         // 131072*768*2 = 201326592
  const size_t WH_OFF  = GI_OFF + 201326592ull;     // w_ih f16: 393216
  const size_t GIK_OFF = WH_OFF + 393216ull;        // 64*768*2 = 98304
  const size_t RG_OFF  = GIK_OFF + 98304ull;        // 16*4*256*4 = 65536
  const size_t G_OFF   = RG_OFF + 65536ull;         // 16*256*4 = 16384
  f16*   GI   = (f16*)(ws + GI_OFF);
  f16*   Wih  = (f16*)(ws + WH_OFF);
  f16*   GIk  = (f16*)(ws + GIK_OFF);
  float* rg   = (float*)(ws + RG_OFF);
  float* g    = (float*)(ws + G_OFF);

  // 1. w_ih -> f16
  cvt_f32_f16<<<dim3(768), dim3(256), 0, stream>>>(w_ih, Wih, G3 * II);
  // 2. GI = x @ w_ih^T + b_ih  (M = 131072)
  gi_gemm<<<dim3(2048), dim3(256), 0, stream>>>(x, Wih, b_ih, GI);
  // 3. GIk = wm_key @ w_ih^T + b_ih  (M = 64; row = kb*16 + l)
  gi_gemm<<<dim3(1), dim3(256), 0, stream>>>(wm_key, Wih, b_ih, GIk);
  // 4. key scan: 4 chains, 16 steps, collect reset gates
  gru_scan<true><<<dim3(4), dim3(512), 0, stream>>>(w_hh, b_hh, GIk, nullptr, rg, 16);
  // 5. gate means over KB
  gate_mean<<<dim3(16), dim3(256), 0, stream>>>(rg, g);
  // 6. main scan: 64 chains, 2048 steps
  gru_scan<false><<<dim3(64), dim3(512), 0, stream>>>(w_hh, b_hh, GI, g, out, 2048);
}

// Round 2
// 3031.717 us; speedup vs baseline: 1.3623x; 1.3623x over previous
//
#include <hip/hip_runtime.h>

typedef _Float16 f16;
typedef _Float16 half8 __attribute__((ext_vector_type(8)));
typedef _Float16 half2v __attribute__((ext_vector_type(2)));
typedef _Float16 half4 __attribute__((ext_vector_type(4)));
typedef float f32x4 __attribute__((ext_vector_type(4)));
typedef unsigned int uint2v __attribute__((ext_vector_type(2)));

#define G3 768

__global__ void cvt_f32_f16(const float* __restrict__ in, f16* __restrict__ out, int n) {
  int i = blockIdx.x * blockDim.x + threadIdx.x;
  if (i < n) out[i] = (f16)in[i];
}

// C[m][n] = sum_k A[m][k] * W[n][k] + b_ih[n] (+ b_hh[n] for n<512)
// Output written PRE-SWIZZLED for the scan kernel:
//   g = n>>8, u = n&255, ww = u>>5, lq = u&15, s = (u>>4)&1
//   g<2: GIri[(((m*8+ww)*16+lq)*4 + g*2 + s]   (f16)
//   g=2: GIn [(((m*8+ww)*16+lq)*2 + s]         (f16)
__global__ __launch_bounds__(256, 2)
void gi_gemm(const float* __restrict__ A, const f16* __restrict__ W,
             const float* __restrict__ b_ih, const float* __restrict__ b_hh,
             f16* __restrict__ GIri, f16* __restrict__ GIn) {
  const int tid = threadIdx.x;
  const int lane = tid & 63;
  const int w = tid >> 6;      // wave 0..3
  const int quad = lane >> 4;  // 0..3
  const int lq = lane & 15;
  const int m0 = blockIdx.x * 64;

  __shared__ __align__(16) f16 Al[64 * 264];
  __shared__ __align__(16) f16 Bl[48 * 264];

  // stage A tile: 64 rows x 256 f32 -> f16 LDS
#pragma unroll
  for (int i = 0; i < 16; ++i) {
    int f = i * 256 + tid;
    int row = f >> 6;
    int c4 = f & 63;
    float4 v = ((const float4*)A)[(size_t)(m0 + row) * 64 + c4];
    half4 hv = {(f16)v.x, (f16)v.y, (f16)v.z, (f16)v.w};
    *(half4*)&Al[row * 264 + c4 * 4] = hv;
  }
  __syncthreads();

  half8 af[8];
#pragma unroll
  for (int kc = 0; kc < 8; ++kc)
    af[kc] = *(half8*)&Al[(w * 16 + lq) * 264 + kc * 32 + quad * 8];

  for (int nc = 0; nc < 16; ++nc) {
    __syncthreads();
    int n0 = nc * 48;
#pragma unroll
    for (int i = 0; i < 6; ++i) {
      int f = i * 256 + tid;
      int row = f >> 5;
      int c8 = f & 31;
      half8 v = ((const half8*)(W + (size_t)(n0 + row) * 256))[c8];
      *(half8*)&Bl[row * 264 + c8 * 8] = v;
    }
    __syncthreads();

    f32x4 acc[3] = {};
#pragma unroll
    for (int kc = 0; kc < 8; ++kc) {
#pragma unroll
      for (int nt = 0; nt < 3; ++nt) {
        half8 bf = *(half8*)&Bl[(nt * 16 + lq) * 264 + kc * 32 + quad * 8];
        acc[nt] = __builtin_amdgcn_mfma_f32_16x16x32_f16(af[kc], bf, acc[nt], 0, 0, 0);
      }
    }
#pragma unroll
    for (int nt = 0; nt < 3; ++nt) {
      int n = n0 + nt * 16 + lq;
      float bv = b_ih[n] + (n < 512 ? b_hh[n] : 0.f);
      int g = n >> 8;
      int u = n & 255;
      int ww = u >> 5, lq16 = u & 15, s = (u >> 4) & 1;
#pragma unroll
      for (int r = 0; r < 4; ++r) {
        int m = m0 + w * 16 + quad * 4 + r;
        float val = acc[nt][r] + bv;
        size_t base = ((size_t)m * 8 + ww) * 16 + lq16;
        if (g < 2) GIri[base * 4 + g * 2 + s] = (f16)val;
        else       GIn[base * 2 + s] = (f16)val;
      }
    }
  }
}

__device__ __forceinline__ float sigf(float x) {
  return __builtin_amdgcn_rcpf(1.f + __expf(-x));
}
__device__ __forceinline__ float tanhf_(float x) {
  return 1.f - 2.f * __builtin_amdgcn_rcpf(__expf(2.f * x) + 1.f);
}

#define MF(af, bw, c) __builtin_amdgcn_mfma_f32_16x16x32_f16(af, bw, c, 0, 0, 0)

#define KC_ALL(af, kc) \
  a0 = MF(af, w0##kc, a0); a1 = MF(af, w1##kc, a1); a2 = MF(af, w2##kc, a2); \
  a3 = MF(af, w3##kc, a3); a4 = MF(af, w4##kc, a4); a5 = MF(af, w5##kc, a5);

#define LOADW(t6, kc) { \
    const float* wr_ = Whh + (size_t)(((t6 >> 1) * 256) + w * 32 + ((t6 & 1) * 16) + lq) * 256 + (kc * 32 + colb); \
    float4 va_ = *(const float4*)wr_; float4 vb_ = *(const float4*)(wr_ + 4); \
    w##t6##kc = (half8){(f16)va_.x, (f16)va_.y, (f16)va_.z, (f16)va_.w, \
                        (f16)vb_.x, (f16)vb_.y, (f16)vb_.z, (f16)vb_.w}; }

#define LOADW_T6(t6) \
  LOADW(t6, 0) LOADW(t6, 1) LOADW(t6, 2) LOADW(t6, 3) \
  LOADW(t6, 4) LOADW(t6, 5) LOADW(t6, 6) LOADW(t6, 7)

#define UNPACK2(u32, lo, hi) { half2v h2_ = __builtin_bit_cast(half2v, (unsigned int)(u32)); \
                               lo = (float)h2_[0]; hi = (float)h2_[1]; }

// One step: MFMA gh into regs (units indexed by lane&15), in-register epilogue,
// quad0 writes hnew to the other h buffer; raw barrier (lgkm only, vmcnt stays
// outstanding so the distance-2 gi prefetch survives the barrier).
#define STEP(tcur, PRI, PN) { \
    const f16* hr_ = &hbuf[(tcur) & 1][0]; \
    f32x4 a0 = {}, a1 = {}, a2 = {}, a3 = {}, a4 = {}, a5 = {}; \
    half8 f0_ = *(const half8*)(hr_ + 0 * 32 + colb); \
    half8 f1_ = *(const half8*)(hr_ + 1 * 32 + colb); \
    half8 f2_ = *(const half8*)(hr_ + 2 * 32 + colb); \
    half8 f3_ = *(const half8*)(hr_ + 3 * 32 + colb); \
    KC_ALL(f0_, 0) \
    half8 f4_ = *(const half8*)(hr_ + 4 * 32 + colb); \
    KC_ALL(f1_, 1) \
    half8 f5_ = *(const half8*)(hr_ + 5 * 32 + colb); \
    KC_ALL(f2_, 2) \
    half8 f6_ = *(const half8*)(hr_ + 6 * 32 + colb); \
    KC_ALL(f3_, 3) \
    half8 f7_ = *(const half8*)(hr_ + 7 * 32 + colb); \
    KC_ALL(f4_, 4) KC_ALL(f5_, 5) KC_ALL(f6_, 6) KC_ALL(f7_, 7) \
    float gr0_, gr1_, gi0_, gi1_, gn0_, gn1_; \
    UNPACK2(PRI[0], gr0_, gr1_); \
    UNPACK2(PRI[1], gi0_, gi1_); \
    UNPACK2(PN, gn0_, gn1_); \
    if ((tcur) + 2 < T) { \
      PRI = *(const uint2v*)(gri + (size_t)((tcur) + 2) * 512); \
      PN = *(const unsigned int*)(gn + (size_t)((tcur) + 2) * 256); \
    } \
    float rg0_ = sigf(gr0_ + a0[0]); \
    float rg1_ = sigf(gr1_ + a1[0]); \
    float ig0_ = sigf(gi0_ + a2[0]); \
    float ig1_ = sigf(gi1_ + a3[0]); \
    float ng0_ = tanhf_(gn0_ + rg0_ * (bn0 + a4[0])); \
    float ng1_ = tanhf_(gn1_ + rg1_ * (bn1 + a5[0])); \
    float hy0_ = ng0_ + ig0_ * (h0 - ng0_); \
    float hy1_ = ng1_ + ig1_ * (h1 - ng1_); \
    if (IS_KEY) { \
      if (quad == 0) { float* o_ = out + ((size_t)(tcur) * nb + b) * 256 + u0; o_[0] = rg0_; o_[16] = rg1_; } \
      h0 = hy0_; h1 = hy1_; \
    } else { \
      if (quad == 0) { float* o_ = out + ((size_t)(tcur) * nb + b) * 256 + u0; o_[0] = hy0_; o_[16] = hy1_; } \
      float gm0_ = 1.f, gm1_ = 1.f; \
      if ((tcur) < 16) { gm0_ = gates[(tcur) * 256 + u0]; gm1_ = gates[(tcur) * 256 + u0 + 16]; } \
      h0 = hy0_ * gm0_; h1 = hy1_ * gm1_; \
    } \
    if (quad == 0) { f16* hw_ = &hbuf[((tcur) + 1) & 1][0]; hw_[u0] = (f16)h0; hw_[u0 + 16] = (f16)h1; } \
    __asm__ volatile("" ::: "memory"); \
    __builtin_amdgcn_s_waitcnt(0xC07F); /* lgkmcnt(0), vmcnt/expcnt unconstrained */ \
    __builtin_amdgcn_s_barrier(); \
    __asm__ volatile("" ::: "memory"); }

// One block per chain, 512 threads (8 waves). W_hh resident in 48 named half8
// B-fragments per wave (192 VGPRs): wave w owns units [w*32, w*32+32), rows
// gate-grouped (t6 0,1 = r; 2,3 = i; 4,5 = n). A operand = h replicated in all
// 16 rows -> D cols = gh, identical in every reg/quad.
template <bool IS_KEY>
__global__ __launch_bounds__(512)
__attribute__((amdgpu_waves_per_eu(2, 2)))
void gru_scan(const float* __restrict__ Whh, const float* __restrict__ bhh,
              const f16* __restrict__ GIri, const f16* __restrict__ GIn,
              const float* __restrict__ gates, float* __restrict__ out, int T) {
  const int tid = threadIdx.x;
  const int lane = tid & 63;
  const int w = tid >> 6;      // 0..7
  const int quad = lane >> 4;  // 0..3
  const int lq = lane & 15;
  const int b = blockIdx.x;
  const int nb = gridDim.x;
  const int colb = quad * 8;
  const int u0 = w * 32 + lq;  // this lane's unit (s=0); s=1 -> u0+16

  __shared__ __align__(16) f16 hbuf[2][256];

  half8 w00, w01, w02, w03, w04, w05, w06, w07;
  half8 w10, w11, w12, w13, w14, w15, w16, w17;
  half8 w20, w21, w22, w23, w24, w25, w26, w27;
  half8 w30, w31, w32, w33, w34, w35, w36, w37;
  half8 w40, w41, w42, w43, w44, w45, w46, w47;
  half8 w50, w51, w52, w53, w54, w55, w56, w57;
  LOADW_T6(0) LOADW_T6(1) LOADW_T6(2) LOADW_T6(3) LOADW_T6(4) LOADW_T6(5)

  if (tid < 256) { hbuf[0][tid] = (f16)0.f; hbuf[1][tid] = (f16)0.f; }

  float h0 = 0.f, h1 = 0.f;
  const float bn0 = bhh[512 + u0];
  const float bn1 = bhh[512 + u0 + 16];

  const size_t mstart = (size_t)b * T;
  const f16* gri = GIri + ((mstart * 8 + w) * 16 + lq) * 4;  // +512 per step
  const f16* gn  = GIn + ((mstart * 8 + w) * 16 + lq) * 2;   // +256 per step

  uint2v priA = *(const uint2v*)(gri);
  unsigned int pnA = *(const unsigned int*)(gn);
  uint2v priB = *(const uint2v*)(gri + 512);
  unsigned int pnB = *(const unsigned int*)(gn + 256);

  __syncthreads();

  for (int t = 0; t < T; t += 2) {
    STEP(t, priA, pnA)
    STEP(t + 1, priB, pnB)
  }
}

__global__ void gate_mean(const float* __restrict__ rg, float* __restrict__ g) {
  int i = blockIdx.x * 256 + threadIdx.x;  // 16*256
  int l = i >> 8;
  int j = i & 255;
  float s = 0.f;
#pragma unroll
  for (int kb = 0; kb < 4; ++kb) s += rg[((size_t)l * 4 + kb) * 256 + j];
  g[i] = 0.25f * s;
}

extern "C" void kernel_launch(void* const* d_in, const int* in_sizes, int n_in,
                              void* d_out, int out_size, void* d_ws, size_t ws_size,
                              hipStream_t stream) {
  const float* x      = (const float*)d_in[0];  // [64][2048][256]
  const float* wm_key = (const float*)d_in[1];  // [4][16][256]
  const float* w_ih   = (const float*)d_in[2];  // [768][256]
  const float* w_hh   = (const float*)d_in[3];  // [768][256]
  const float* b_ih   = (const float*)d_in[4];  // [768]
  const float* b_hh   = (const float*)d_in[5];  // [768]
  float* out = (float*)d_out;                   // [2048][64][256]

  char* ws = (char*)d_ws;
  const size_t GIRI_OFF  = 0;                          // 131072*512*2 = 134217728
  const size_t GIN_OFF   = GIRI_OFF + 134217728ull;    // 131072*256*2 = 67108864
  const size_t WIH_OFF   = GIN_OFF + 67108864ull;      // 768*256*2 = 393216
  const size_t GIKRI_OFF = WIH_OFF + 393216ull;        // 64*512*2 = 65536
  const size_t GIKN_OFF  = GIKRI_OFF + 65536ull;       // 64*256*2 = 32768
  const size_t RG_OFF    = GIKN_OFF + 32768ull;        // 16*4*256*4 = 65536
  const size_t G_OFF     = RG_OFF + 65536ull;          // 16*256*4 = 16384
  f16*   GIri  = (f16*)(ws + GIRI_OFF);
  f16*   GIn   = (f16*)(ws + GIN_OFF);
  f16*   Wih   = (f16*)(ws + WIH_OFF);
  f16*   GIkri = (f16*)(ws + GIKRI_OFF);
  f16*   GIkn  = (f16*)(ws + GIKN_OFF);
  float* rg    = (float*)(ws + RG_OFF);
  float* g     = (float*)(ws + G_OFF);

  cvt_f32_f16<<<dim3(768), dim3(256), 0, stream>>>(w_ih, Wih, G3 * 256);
  gi_gemm<<<dim3(2048), dim3(256), 0, stream>>>(x, Wih, b_ih, b_hh, GIri, GIn);
  gi_gemm<<<dim3(1), dim3(256), 0, stream>>>(wm_key, Wih, b_ih, b_hh, GIkri, GIkn);
  gru_scan<true><<<dim3(4), dim3(512), 0, stream>>>(w_hh, b_hh, GIkri, GIkn, g, rg, 16);
  gate_mean<<<dim3(16), dim3(256), 0, stream>>>(rg, g);
  gru_scan<false><<<dim3(64), dim3(512), 0, stream>>>(w_hh, b_hh, GIri, GIn, g, out, 2048);
}